// Round 7
// baseline (247.521 us; speedup 1.0000x reference)
//
#include <hip/hip_runtime.h>
#include <hip/hip_fp16.h>

#define LRELU(v) ((v) > 0.f ? (v) : 0.2f * (v))

typedef _Float16 f16;
typedef __attribute__((ext_vector_type(4))) _Float16 f16x4;
typedef __attribute__((ext_vector_type(8))) _Float16 f16x8;
typedef __attribute__((ext_vector_type(4))) float    f32x4;

// swizzled byte offset inside a [rows][128 halves] LDS/global tile (256B rows)
__device__ __forceinline__ int swz(int row, int kbyte) {
    return (row * 256 + kbyte) ^ ((row & 7) << 4);
}

// ================================================================ CSR build
constexpr int NPB    = 128;
constexpr int MAXBUK = 512;    // n <= 65536  (also guarantees src fits 16 bits)
constexpr int EPB    = 2048;   // edges per block in bucket passes
constexpr int CAP    = 12288;

__global__ void zero_kernel(int* __restrict__ p, int n) {
    int i = blockIdx.x * blockDim.x + threadIdx.x;
    if (i < n) p[i] = 0;
}

__global__ __launch_bounds__(256) void bucket_hist_kernel(
    const int* __restrict__ ei, int* __restrict__ bcnt, int E, int tot, int nbuk) {
    __shared__ int lh[MAXBUK];
    for (int i = threadIdx.x; i < nbuk; i += 256) lh[i] = 0;
    __syncthreads();
    int base = blockIdx.x * EPB;
    int lim  = min(base + EPB, tot);
    for (int e = base + threadIdx.x; e < lim; e += 256) {
        int dst = (e < E) ? ei[E + e] : (e - E);
        atomicAdd(&lh[dst >> 7], 1);
    }
    __syncthreads();
    for (int i = threadIdx.x; i < nbuk; i += 256)
        if (lh[i]) atomicAdd(&bcnt[i], lh[i]);
}

__global__ __launch_bounds__(512) void bucket_scan_kernel(
    const int* __restrict__ bcnt, int* __restrict__ boff, int* __restrict__ bcur,
    int* __restrict__ csr_off, int nbuk, int n, int tot) {
    __shared__ int s[512];
    int t = threadIdx.x;
    int v0 = (t < nbuk) ? bcnt[t] : 0;
    s[t] = v0;
    __syncthreads();
    for (int d = 1; d < 512; d <<= 1) {
        int v = (t >= d) ? s[t - d] : 0;
        __syncthreads();
        s[t] += v;
        __syncthreads();
    }
    if (t < nbuk) {
        int off = s[t] - v0;
        boff[t] = off;
        bcur[t] = off;
    }
    if (t == 0) { boff[nbuk] = tot; csr_off[n] = tot; }
}

// packs (src, dst&127) into one uint: src in [15:0], dlocal in [22:16]
__global__ __launch_bounds__(256) void bucket_scatter_kernel(
    const int* __restrict__ ei, int* __restrict__ bcur,
    unsigned int* __restrict__ be, int E, int tot, int nbuk) {
    __shared__ int lh[MAXBUK];
    __shared__ int lb[MAXBUK];
    for (int i = threadIdx.x; i < nbuk; i += 256) lh[i] = 0;
    __syncthreads();
    int base = blockIdx.x * EPB;
    int lim  = min(base + EPB, tot);
    for (int e = base + threadIdx.x; e < lim; e += 256) {
        int dst = (e < E) ? ei[E + e] : (e - E);
        atomicAdd(&lh[dst >> 7], 1);
    }
    __syncthreads();
    for (int i = threadIdx.x; i < nbuk; i += 256)
        lb[i] = lh[i] ? atomicAdd(&bcur[i], lh[i]) : 0;
    __syncthreads();
    for (int i = threadIdx.x; i < nbuk; i += 256) lh[i] = 0;
    __syncthreads();
    for (int e = base + threadIdx.x; e < lim; e += 256) {
        int src, dst;
        if (e < E) { src = ei[e]; dst = ei[E + e]; }
        else       { src = dst = e - E; }
        int b = dst >> 7;
        int p = lb[b] + atomicAdd(&lh[b], 1);
        be[p] = (unsigned)src | ((unsigned)(dst & (NPB - 1)) << 16);
    }
}

__global__ __launch_bounds__(256) void csr_build_kernel(
    const unsigned int* __restrict__ be, const int* __restrict__ boff,
    int* __restrict__ csr_off, int* __restrict__ csr_src, int n) {
    __shared__ int hist[NPB];
    __shared__ int sc[NPB];
    __shared__ int cur[NPB];
    __shared__ int stage[CAP];
    const int b = blockIdx.x, t = threadIdx.x;
    const int start = boff[b], end = boff[b + 1], cnt = end - start;
    if (t < NPB) hist[t] = 0;
    __syncthreads();
    for (int i = t; i < cnt; i += 256)
        atomicAdd(&hist[be[start + i] >> 16], 1);
    __syncthreads();
    if (t < NPB) sc[t] = hist[t];
    __syncthreads();
    for (int d = 1; d < NPB; d <<= 1) {
        int v = (t < NPB && t >= d) ? sc[t - d] : 0;
        __syncthreads();
        if (t < NPB) sc[t] += v;
        __syncthreads();
    }
    if (t < NPB) {
        int excl = sc[t] - hist[t];
        cur[t] = excl;
        int node = b * NPB + t;
        if (node < n) csr_off[node] = start + excl;
    }
    __syncthreads();
    if (cnt <= CAP) {
        for (int i = t; i < cnt; i += 256) {
            unsigned v = be[start + i];
            int p = atomicAdd(&cur[v >> 16], 1);
            stage[p] = (int)(v & 0xFFFFu);
        }
        __syncthreads();
        for (int i = t; i < cnt; i += 256) csr_src[start + i] = stage[i];
    } else {
        for (int i = t; i < cnt; i += 256) {
            unsigned v = be[start + i];
            int p = atomicAdd(&cur[v >> 16], 1);
            csr_src[start + p] = (int)(v & 0xFFFFu);
        }
    }
}

// ---------------- legacy CSR path (fallback, n > 65536 etc.)
__global__ void hist_kernel(const int* __restrict__ ei, int* __restrict__ counts,
                            int E, int tot) {
    int e = blockIdx.x * blockDim.x + threadIdx.x;
    if (e >= tot) return;
    int dst = (e < E) ? ei[E + e] : (e - E);
    atomicAdd(&counts[dst], 1);
}

__global__ __launch_bounds__(1024) void scan_kernel(const int* __restrict__ counts,
                                                    int* __restrict__ csr_off,
                                                    int* __restrict__ cursor, int n) {
    __shared__ int part[1024];
    int t = threadIdx.x;
    int chunk = (n + 1023) >> 10;
    int lo = t * chunk, hi = min(lo + chunk, n);
    int sum = 0;
    for (int i = lo; i < hi; ++i) sum += counts[i];
    part[t] = sum;
    __syncthreads();
    for (int d = 1; d < 1024; d <<= 1) {
        int add = (t >= d) ? part[t - d] : 0;
        __syncthreads();
        part[t] += add;
        __syncthreads();
    }
    int run = part[t] - sum;
    for (int i = lo; i < hi; ++i) {
        csr_off[i] = run;
        cursor[i]  = run;
        run += counts[i];
    }
    if (t == 1023) csr_off[n] = part[1023];
}

__global__ void scatter_kernel(const int* __restrict__ ei, int* __restrict__ cursor,
                               int* __restrict__ csr_src, int E, int tot) {
    int e = blockIdx.x * blockDim.x + threadIdx.x;
    if (e >= tot) return;
    int src, dst;
    if (e < E) { src = ei[e]; dst = ei[E + e]; }
    else       { src = dst = e - E; }
    int pos = atomicAdd(&cursor[dst], 1);
    csr_src[pos] = src;
}

// ============================================ W prep: transpose+split+swizzle
__global__ void prep_w_kernel(const float* __restrict__ W, f16* __restrict__ WhT,
                              f16* __restrict__ WlT, int ncol) {
    int idx = blockIdx.x * 256 + threadIdx.x;
    if (idx >= 128 * ncol) return;
    int k = idx / ncol, c = idx % ncol;
    float v = W[idx];
    f16 h = (f16)v;
    f16 l = (f16)(v - (float)h);
    int byte = swz(c, k * 2);
    *(f16*)((char*)WhT + byte) = h;
    *(f16*)((char*)WlT + byte) = l;
}

// ============================================ split-fp16 MFMA GEMM + attn halves
// feat[n,NCOL](f16) = x[n,128](f32) @ W[128,NCOL]  (3-term split fp16 MFMA)
// Fused epilogue: alsrc/aldst per-head dots from the fp32 accumulators.
// C/D frag: col = ct*16 + (lane&15), row = (lane>>4)*4 + reg  [m89-verified].
template <int NCOL, int HEADS>
__global__ __launch_bounds__(256) void gemm_mfma_kernel(
    const float* __restrict__ x, const f16* __restrict__ WhT,
    const f16* __restrict__ WlT, const float* __restrict__ a_src,
    const float* __restrict__ a_dst, __half* __restrict__ feat,
    float* __restrict__ alsrc, float* __restrict__ aldst, int n) {
    constexpr int ROWS = 64;
    constexpr int NCT  = NCOL / 16;
    constexpr int CTH  = (NCOL / HEADS) / 16;   // col-tiles per head: 2 (L1) / 4 (L2)
    __shared__ char Xh[ROWS * 256];
    __shared__ char Xl[ROWS * 256];
    __shared__ char Wh[NCOL * 256];
    __shared__ char Wl[NCOL * 256];
    const int t  = threadIdx.x;
    const int r0 = blockIdx.x * ROWS;

    {   // stage W: linear copy (pre-swizzled in global)
        const float4* sh = (const float4*)WhT;
        const float4* sl = (const float4*)WlT;
        float4* dh = (float4*)Wh;
        float4* dl = (float4*)Wl;
        for (int i = t; i < NCOL * 16; i += 256) { dh[i] = sh[i]; dl[i] = sl[i]; }
    }
    {   // stage X: fp32 -> (hi,lo) f16, swizzled
        const float4* X4 = (const float4*)x;
        for (int i = t; i < ROWS * 32; i += 256) {
            int row = i >> 5, k4 = i & 31;
            float4 v = (r0 + row < n) ? X4[(size_t)(r0 + row) * 32 + k4]
                                      : make_float4(0.f, 0.f, 0.f, 0.f);
            f16x4 h, l;
            h[0] = (f16)v.x; l[0] = (f16)(v.x - (float)h[0]);
            h[1] = (f16)v.y; l[1] = (f16)(v.y - (float)h[1]);
            h[2] = (f16)v.z; l[2] = (f16)(v.z - (float)h[2]);
            h[3] = (f16)v.w; l[3] = (f16)(v.w - (float)h[3]);
            int byte = swz(row, k4 * 8);
            *(f16x4*)(Xh + byte) = h;
            *(f16x4*)(Xl + byte) = l;
        }
    }
    __syncthreads();

    const int w  = t >> 6, l = t & 63;
    const int lr = l & 15, lg = l >> 4;
    const int arow = w * 16 + lr;

    f32x4 acc[NCT];
#pragma unroll
    for (int ct = 0; ct < NCT; ++ct) acc[ct] = (f32x4){0.f, 0.f, 0.f, 0.f};

#pragma unroll
    for (int kt = 0; kt < 4; ++kt) {
        const int ka = kt * 64 + 8 * lg;
        f16x4 al0 = *(const f16x4*)(Xh + swz(arow, ka));
        f16x4 al1 = *(const f16x4*)(Xh + swz(arow, ka + 32));
        f16x4 am0 = *(const f16x4*)(Xl + swz(arow, ka));
        f16x4 am1 = *(const f16x4*)(Xl + swz(arow, ka + 32));
        f16x8 a_h = __builtin_shufflevector(al0, al1, 0, 1, 2, 3, 4, 5, 6, 7);
        f16x8 a_l = __builtin_shufflevector(am0, am1, 0, 1, 2, 3, 4, 5, 6, 7);
#pragma unroll
        for (int ct = 0; ct < NCT; ++ct) {
            const int col = ct * 16 + lr;
            f16x4 b0 = *(const f16x4*)(Wh + swz(col, ka));
            f16x4 b1 = *(const f16x4*)(Wh + swz(col, ka + 32));
            f16x4 c0 = *(const f16x4*)(Wl + swz(col, ka));
            f16x4 c1 = *(const f16x4*)(Wl + swz(col, ka + 32));
            f16x8 b_h = __builtin_shufflevector(b0, b1, 0, 1, 2, 3, 4, 5, 6, 7);
            f16x8 b_l = __builtin_shufflevector(c0, c1, 0, 1, 2, 3, 4, 5, 6, 7);
            acc[ct] = __builtin_amdgcn_mfma_f32_16x16x32_f16(a_h, b_h, acc[ct], 0, 0, 0);
            acc[ct] = __builtin_amdgcn_mfma_f32_16x16x32_f16(a_l, b_h, acc[ct], 0, 0, 0);
            acc[ct] = __builtin_amdgcn_mfma_f32_16x16x32_f16(a_h, b_l, acc[ct], 0, 0, 0);
        }
    }

    // feat write (fp16)
#pragma unroll
    for (int ct = 0; ct < NCT; ++ct)
#pragma unroll
        for (int r = 0; r < 4; ++r) {
            int grow = r0 + w * 16 + lg * 4 + r;
            if (grow < n)
                feat[(size_t)grow * NCOL + ct * 16 + lr] = __float2half(acc[ct][r]);
        }

    // fused attention halves: per row, per head: sum_col acc*a  (16-lane reduce)
    float as[NCT], av[NCT];
#pragma unroll
    for (int ct = 0; ct < NCT; ++ct) {
        as[ct] = a_src[ct * 16 + lr];
        av[ct] = a_dst[ct * 16 + lr];
    }
#pragma unroll
    for (int r = 0; r < 4; ++r) {
        int grow = r0 + w * 16 + lg * 4 + r;
#pragma unroll
        for (int h = 0; h < HEADS; ++h) {
            float s = 0.f, d = 0.f;
#pragma unroll
            for (int q = 0; q < CTH; ++q) {
                int ct = h * CTH + q;
                s += acc[ct][r] * as[ct];
                d += acc[ct][r] * av[ct];
            }
#pragma unroll
            for (int o = 1; o < 16; o <<= 1) {
                s += __shfl_xor(s, o);
                d += __shfl_xor(d, o);
            }
            if (lr == 0 && grow < n) {
                alsrc[grow * HEADS + h] = s;
                aldst[grow * HEADS + h] = d;
            }
        }
    }
}

// ==================== fused softmax + aggregation (one wave per dst node)
// Two-phase batches: phase 1 computes p = exp(LRELU(alsrc[src]+aldst)) with ONE
// lane per (edge,head) -> 1 expf per (edge,head) instead of LPE duplicates;
// stores p to a wave-private LDS buffer. Phase 2 streams the feat gathers with
// p broadcast from LDS. No max-subtraction (logits bounded, softmax
// shift-invariant); sume reduced per head-class; deg >= 1 (self-loop).
template <int OUTC, int HEADS, bool DO_ELU>
__global__ __launch_bounds__(256) void aggregate_kernel(
    const int* __restrict__ csr_off, const int* __restrict__ csr_src,
    const float* __restrict__ alsrc, const float* __restrict__ aldst,
    const __half* __restrict__ feat, const float* __restrict__ bias,
    float* __restrict__ out, int n) {
    constexpr int CPL = 8;            // cols per lane (16B of fp16)
    constexpr int LPE = OUTC / CPL;   // lanes per edge slot: 16 (L1) / 8 (L2)
    constexpr int EPW = 64 / LPE;     // edge slots per wave:  4 / 8
    constexpr int HID = OUTC / HEADS;
    constexpr int B   = 64 / HEADS;   // edges per batch: 16 (L1) / 64 (L2)
    __shared__ float pbuf[4][64];
    const int wid  = threadIdx.x >> 6;
    const int lane = threadIdx.x & 63;
    int node = blockIdx.x * 4 + wid;
    if (node >= n) return;
    const int off = csr_off[node];
    const int deg = csr_off[node + 1] - off;

    // phase-1 mapping: lane = e1*HEADS + h1
    const int   e1  = lane / HEADS;
    const int   h1  = lane & (HEADS - 1);
    const float ad1 = aldst[node * HEADS + h1];
    // phase-2 mapping: lane = sub*LPE + l, cols [CPL*l, CPL*l+CPL)
    const int sub = lane / LPE;
    const int l   = lane % LPE;
    const int h2  = (CPL * l) / HID;

    float acc[CPL];
#pragma unroll
    for (int c = 0; c < CPL; ++c) acc[c] = 0.f;
    float sume = 0.f;

    for (int base = 0; base < deg; base += B) {
        const int bcnt = min(B, deg - base);
        // ---- phase 1: p for (edge,head), one lane each
        float p = 0.f;
        if (e1 < bcnt) {
            int   s = csr_src[off + base + e1];
            float e = alsrc[(size_t)s * HEADS + h1] + ad1;
            e = LRELU(e);
            p = __expf(e);
        }
        pbuf[wid][lane] = p;   // index = e_local*HEADS + h
        sume += p;
        // ---- phase 2: gather + FMA stream
#pragma unroll 2
        for (int i = sub; i < bcnt; i += EPW) {
            int   s  = csr_src[off + base + i];
            float pp = pbuf[wid][i * HEADS + h2];
            const float4   fv = *(const float4*)(feat + (size_t)s * OUTC + CPL * l);
            const __half2* hp = (const __half2*)&fv;
#pragma unroll
            for (int c2 = 0; c2 < 4; ++c2) {
                float2 f2 = __half22float2(hp[c2]);
                acc[2 * c2 + 0] += pp * f2.x;
                acc[2 * c2 + 1] += pp * f2.y;
            }
        }
    }
    // sume: reduce preserving head class (phase-1 classes: lane & (HEADS-1))
#pragma unroll
    for (int o = HEADS; o < 64; o <<= 1) sume += __shfl_xor(sume, o);
    const float sume_h = __shfl(sume, h2);   // lane h2 holds head h2's total
    // acc: butterfly across edge slots (disjoint edge subsets)
#pragma unroll
    for (int o = LPE; o < 64; o <<= 1)
#pragma unroll
        for (int c = 0; c < CPL; ++c) acc[c] += __shfl_xor(acc[c], o);

    if (sub == 0) {
        const float inv = 1.f / sume_h;
        float v[CPL];
#pragma unroll
        for (int c = 0; c < CPL; ++c) {
            v[c] = acc[c] * inv + bias[CPL * l + c];
            if (DO_ELU) v[c] = (v[c] > 0.f) ? v[c] : expm1f(v[c]);
        }
        float* op = out + (size_t)node * OUTC + CPL * l;
        *(float4*)(op + 0) = make_float4(v[0], v[1], v[2], v[3]);
        *(float4*)(op + 4) = make_float4(v[4], v[5], v[6], v[7]);
    }
}

// ----------------------------------------------------------------- launcher
extern "C" void kernel_launch(void* const* d_in, const int* in_sizes, int n_in,
                              void* d_out, int out_size, void* d_ws, size_t ws_size,
                              hipStream_t stream) {
    const float* x   = (const float*)d_in[0];
    const int*   ei  = (const int*)d_in[1];
    const float* W1  = (const float*)d_in[2];
    const float* a1s = (const float*)d_in[3];
    const float* a1d = (const float*)d_in[4];
    const float* b1  = (const float*)d_in[5];
    const float* W2  = (const float*)d_in[6];
    const float* a2s = (const float*)d_in[7];
    const float* a2d = (const float*)d_in[8];
    const float* b2  = (const float*)d_in[9];
    float*       out = (float*)d_out;

    constexpr int IN_C = 128, HEADS = 4, OUTC1 = 128, OUTC2 = 64;
    const int n    = in_sizes[0] / IN_C;
    const int E    = in_sizes[1] / 2;
    const int tot  = E + n;
    const int nbuk = (n + NPB - 1) / NPB;

    char* w = (char*)d_ws;
    auto  alloc = [&](size_t bytes) -> char* {
        char* p = w;
        w += (bytes + 255) & ~(size_t)255;
        return p;
    };
    int*    bcnt    = (int*)alloc((size_t)MAXBUK * 4);
    int*    boff    = (int*)alloc((size_t)(MAXBUK + 1) * 4);
    int*    bcur    = (int*)alloc((size_t)MAXBUK * 4);
    int*    csr_off = (int*)alloc((size_t)(n + 1) * 4);
    int*    csr_src = (int*)alloc((size_t)tot * 4);
    size_t  be_sz   = (size_t)tot * 4 > (size_t)2 * n * 4 ? (size_t)tot * 4
                                                          : (size_t)2 * n * 4;
    unsigned int* be = (unsigned int*)alloc(be_sz);   // packed (src | dlocal<<16)
    size_t  csr_need = (size_t)(w - (char*)d_ws);
    f16*    wh1     = (f16*)alloc(128 * 256);
    f16*    wl1     = (f16*)alloc(128 * 256);
    f16*    wh2     = (f16*)alloc(64 * 256);
    f16*    wl2     = (f16*)alloc(64 * 256);
    float*  alsrc1  = (float*)alloc((size_t)n * HEADS * 4);
    float*  aldst1  = (float*)alloc((size_t)n * HEADS * 4);
    float*  alsrc2  = (float*)alloc((size_t)n * 4);
    float*  aldst2  = (float*)alloc((size_t)n * 4);
    __half* feat_h  = (__half*)alloc((size_t)n * OUTC1 * 2);
    float*  y1      = (float*)alloc((size_t)n * OUTC1 * 4);
    const bool new_csr = (nbuk <= MAXBUK) && (csr_need <= ws_size);

    // ---- W prep (both layers)
    prep_w_kernel<<<(128 * OUTC1 + 255) / 256, 256, 0, stream>>>(W1, wh1, wl1, OUTC1);
    prep_w_kernel<<<(128 * OUTC2 + 255) / 256, 256, 0, stream>>>(W2, wh2, wl2, OUTC2);

    // ---- CSR (shared by both layers)
    if (new_csr) {
        const int g1 = (tot + EPB - 1) / EPB;
        zero_kernel<<<(nbuk + 255) / 256, 256, 0, stream>>>(bcnt, nbuk);
        bucket_hist_kernel<<<g1, 256, 0, stream>>>(ei, bcnt, E, tot, nbuk);
        bucket_scan_kernel<<<1, 512, 0, stream>>>(bcnt, boff, bcur, csr_off, nbuk, n, tot);
        bucket_scatter_kernel<<<g1, 256, 0, stream>>>(ei, bcur, be, E, tot, nbuk);
        csr_build_kernel<<<nbuk, 256, 0, stream>>>(be, boff, csr_off, csr_src, n);
    } else {
        int* counts = (int*)be;
        int* cursor = counts + n;
        zero_kernel<<<(n + 255) / 256, 256, 0, stream>>>(counts, n);
        hist_kernel<<<(tot + 255) / 256, 256, 0, stream>>>(ei, counts, E, tot);
        scan_kernel<<<1, 1024, 0, stream>>>(counts, csr_off, cursor, n);
        scatter_kernel<<<(tot + 255) / 256, 256, 0, stream>>>(ei, cursor, csr_src, E, tot);
    }

    const int gblk = (n + 63) / 64;
    // ---- layer 1: GATConv(128 -> 4 x 32), concat, +b1, ELU
    gemm_mfma_kernel<OUTC1, HEADS><<<gblk, 256, 0, stream>>>(
        x, wh1, wl1, a1s, a1d, feat_h, alsrc1, aldst1, n);
    aggregate_kernel<OUTC1, HEADS, true><<<(n + 3) / 4, 256, 0, stream>>>(
        csr_off, csr_src, alsrc1, aldst1, feat_h, b1, y1, n);

    // ---- layer 2: GATConv(128 -> 1 x 64), +b2
    gemm_mfma_kernel<OUTC2, 1><<<gblk, 256, 0, stream>>>(
        y1, wh2, wl2, a2s, a2d, feat_h, alsrc2, aldst2, n);
    aggregate_kernel<OUTC2, 1, false><<<(n + 3) / 4, 256, 0, stream>>>(
        csr_off, csr_src, alsrc2, aldst2, feat_h, b2, out, n);
}

// Round 8
// 234.063 us; speedup vs baseline: 1.0575x; 1.0575x over previous
//
#include <hip/hip_runtime.h>
#include <hip/hip_fp16.h>

#define LRELU(v) ((v) > 0.f ? (v) : 0.2f * (v))

typedef _Float16 f16;
typedef __attribute__((ext_vector_type(4))) _Float16 f16x4;
typedef __attribute__((ext_vector_type(8))) _Float16 f16x8;
typedef __attribute__((ext_vector_type(4))) float    f32x4;

// swizzled byte offset inside a [rows][128 halves] LDS/global tile (256B rows)
__device__ __forceinline__ int swz(int row, int kbyte) {
    return (row * 256 + kbyte) ^ ((row & 7) << 4);
}

// ================================================================ CSR build
constexpr int NPB    = 128;
constexpr int MAXBUK = 512;    // n <= 65536  (also guarantees src fits 16 bits)
constexpr int EPB    = 2048;   // edges per block in bucket passes
constexpr int CAP    = 12288;

__global__ void zero_kernel(int* __restrict__ p, int n) {
    int i = blockIdx.x * blockDim.x + threadIdx.x;
    if (i < n) p[i] = 0;
}

__global__ __launch_bounds__(256) void bucket_hist_kernel(
    const int* __restrict__ ei, int* __restrict__ bcnt, int E, int tot, int nbuk) {
    __shared__ int lh[MAXBUK];
    for (int i = threadIdx.x; i < nbuk; i += 256) lh[i] = 0;
    __syncthreads();
    int base = blockIdx.x * EPB;
    int lim  = min(base + EPB, tot);
    for (int e = base + threadIdx.x; e < lim; e += 256) {
        int dst = (e < E) ? ei[E + e] : (e - E);
        atomicAdd(&lh[dst >> 7], 1);
    }
    __syncthreads();
    for (int i = threadIdx.x; i < nbuk; i += 256)
        if (lh[i]) atomicAdd(&bcnt[i], lh[i]);
}

__global__ __launch_bounds__(512) void bucket_scan_kernel(
    const int* __restrict__ bcnt, int* __restrict__ boff, int* __restrict__ bcur,
    int* __restrict__ csr_off, int nbuk, int n, int tot) {
    __shared__ int s[512];
    int t = threadIdx.x;
    int v0 = (t < nbuk) ? bcnt[t] : 0;
    s[t] = v0;
    __syncthreads();
    for (int d = 1; d < 512; d <<= 1) {
        int v = (t >= d) ? s[t - d] : 0;
        __syncthreads();
        s[t] += v;
        __syncthreads();
    }
    if (t < nbuk) {
        int off = s[t] - v0;
        boff[t] = off;
        bcur[t] = off;
    }
    if (t == 0) { boff[nbuk] = tot; csr_off[n] = tot; }
}

// packs (src, dst&127) into one uint: src in [15:0], dlocal in [22:16]
__global__ __launch_bounds__(256) void bucket_scatter_kernel(
    const int* __restrict__ ei, int* __restrict__ bcur,
    unsigned int* __restrict__ be, int E, int tot, int nbuk) {
    __shared__ int lh[MAXBUK];
    __shared__ int lb[MAXBUK];
    for (int i = threadIdx.x; i < nbuk; i += 256) lh[i] = 0;
    __syncthreads();
    int base = blockIdx.x * EPB;
    int lim  = min(base + EPB, tot);
    for (int e = base + threadIdx.x; e < lim; e += 256) {
        int dst = (e < E) ? ei[E + e] : (e - E);
        atomicAdd(&lh[dst >> 7], 1);
    }
    __syncthreads();
    for (int i = threadIdx.x; i < nbuk; i += 256)
        lb[i] = lh[i] ? atomicAdd(&bcur[i], lh[i]) : 0;
    __syncthreads();
    for (int i = threadIdx.x; i < nbuk; i += 256) lh[i] = 0;
    __syncthreads();
    for (int e = base + threadIdx.x; e < lim; e += 256) {
        int src, dst;
        if (e < E) { src = ei[e]; dst = ei[E + e]; }
        else       { src = dst = e - E; }
        int b = dst >> 7;
        int p = lb[b] + atomicAdd(&lh[b], 1);
        be[p] = (unsigned)src | ((unsigned)(dst & (NPB - 1)) << 16);
    }
}

__global__ __launch_bounds__(256) void csr_build_kernel(
    const unsigned int* __restrict__ be, const int* __restrict__ boff,
    int* __restrict__ csr_off, int* __restrict__ csr_src, int n) {
    __shared__ int hist[NPB];
    __shared__ int sc[NPB];
    __shared__ int cur[NPB];
    __shared__ int stage[CAP];
    const int b = blockIdx.x, t = threadIdx.x;
    const int start = boff[b], end = boff[b + 1], cnt = end - start;
    if (t < NPB) hist[t] = 0;
    __syncthreads();
    for (int i = t; i < cnt; i += 256)
        atomicAdd(&hist[be[start + i] >> 16], 1);
    __syncthreads();
    if (t < NPB) sc[t] = hist[t];
    __syncthreads();
    for (int d = 1; d < NPB; d <<= 1) {
        int v = (t < NPB && t >= d) ? sc[t - d] : 0;
        __syncthreads();
        if (t < NPB) sc[t] += v;
        __syncthreads();
    }
    if (t < NPB) {
        int excl = sc[t] - hist[t];
        cur[t] = excl;
        int node = b * NPB + t;
        if (node < n) csr_off[node] = start + excl;
    }
    __syncthreads();
    if (cnt <= CAP) {
        for (int i = t; i < cnt; i += 256) {
            unsigned v = be[start + i];
            int p = atomicAdd(&cur[v >> 16], 1);
            stage[p] = (int)(v & 0xFFFFu);
        }
        __syncthreads();
        for (int i = t; i < cnt; i += 256) csr_src[start + i] = stage[i];
    } else {
        for (int i = t; i < cnt; i += 256) {
            unsigned v = be[start + i];
            int p = atomicAdd(&cur[v >> 16], 1);
            csr_src[start + p] = (int)(v & 0xFFFFu);
        }
    }
}

// ---------------- legacy CSR path (fallback, n > 65536 etc.)
__global__ void hist_kernel(const int* __restrict__ ei, int* __restrict__ counts,
                            int E, int tot) {
    int e = blockIdx.x * blockDim.x + threadIdx.x;
    if (e >= tot) return;
    int dst = (e < E) ? ei[E + e] : (e - E);
    atomicAdd(&counts[dst], 1);
}

__global__ __launch_bounds__(1024) void scan_kernel(const int* __restrict__ counts,
                                                    int* __restrict__ csr_off,
                                                    int* __restrict__ cursor, int n) {
    __shared__ int part[1024];
    int t = threadIdx.x;
    int chunk = (n + 1023) >> 10;
    int lo = t * chunk, hi = min(lo + chunk, n);
    int sum = 0;
    for (int i = lo; i < hi; ++i) sum += counts[i];
    part[t] = sum;
    __syncthreads();
    for (int d = 1; d < 1024; d <<= 1) {
        int add = (t >= d) ? part[t - d] : 0;
        __syncthreads();
        part[t] += add;
        __syncthreads();
    }
    int run = part[t] - sum;
    for (int i = lo; i < hi; ++i) {
        csr_off[i] = run;
        cursor[i]  = run;
        run += counts[i];
    }
    if (t == 1023) csr_off[n] = part[1023];
}

__global__ void scatter_kernel(const int* __restrict__ ei, int* __restrict__ cursor,
                               int* __restrict__ csr_src, int E, int tot) {
    int e = blockIdx.x * blockDim.x + threadIdx.x;
    if (e >= tot) return;
    int src, dst;
    if (e < E) { src = ei[e]; dst = ei[E + e]; }
    else       { src = dst = e - E; }
    int pos = atomicAdd(&cursor[dst], 1);
    csr_src[pos] = src;
}

// ============================================ W prep: transpose+split+swizzle
__global__ void prep_w_kernel(const float* __restrict__ W, f16* __restrict__ WhT,
                              f16* __restrict__ WlT, int ncol) {
    int idx = blockIdx.x * 256 + threadIdx.x;
    if (idx >= 128 * ncol) return;
    int k = idx / ncol, c = idx % ncol;
    float v = W[idx];
    f16 h = (f16)v;
    f16 l = (f16)(v - (float)h);
    int byte = swz(c, k * 2);
    *(f16*)((char*)WhT + byte) = h;
    *(f16*)((char*)WlT + byte) = l;
}

// ============================================ split-fp16 MFMA GEMM + attn halves
// feat[n,NCOL](f16) = x[n,128](f32) @ W[128,NCOL]  (3-term split fp16 MFMA)
// Fused epilogue: alsrc/aldst per-head dots from the fp32 accumulators.
// C/D frag: col = ct*16 + (lane&15), row = (lane>>4)*4 + reg  [m89-verified].
template <int NCOL, int HEADS>
__global__ __launch_bounds__(256) void gemm_mfma_kernel(
    const float* __restrict__ x, const f16* __restrict__ WhT,
    const f16* __restrict__ WlT, const float* __restrict__ a_src,
    const float* __restrict__ a_dst, __half* __restrict__ feat,
    float* __restrict__ alsrc, float* __restrict__ aldst, int n) {
    constexpr int ROWS = 64;
    constexpr int NCT  = NCOL / 16;
    constexpr int CTH  = (NCOL / HEADS) / 16;   // col-tiles per head: 2 (L1) / 4 (L2)
    __shared__ char Xh[ROWS * 256];
    __shared__ char Xl[ROWS * 256];
    __shared__ char Wh[NCOL * 256];
    __shared__ char Wl[NCOL * 256];
    const int t  = threadIdx.x;
    const int r0 = blockIdx.x * ROWS;

    {   // stage W: linear copy (pre-swizzled in global)
        const float4* sh = (const float4*)WhT;
        const float4* sl = (const float4*)WlT;
        float4* dh = (float4*)Wh;
        float4* dl = (float4*)Wl;
        for (int i = t; i < NCOL * 16; i += 256) { dh[i] = sh[i]; dl[i] = sl[i]; }
    }
    {   // stage X: fp32 -> (hi,lo) f16, swizzled
        const float4* X4 = (const float4*)x;
        for (int i = t; i < ROWS * 32; i += 256) {
            int row = i >> 5, k4 = i & 31;
            float4 v = (r0 + row < n) ? X4[(size_t)(r0 + row) * 32 + k4]
                                      : make_float4(0.f, 0.f, 0.f, 0.f);
            f16x4 h, l;
            h[0] = (f16)v.x; l[0] = (f16)(v.x - (float)h[0]);
            h[1] = (f16)v.y; l[1] = (f16)(v.y - (float)h[1]);
            h[2] = (f16)v.z; l[2] = (f16)(v.z - (float)h[2]);
            h[3] = (f16)v.w; l[3] = (f16)(v.w - (float)h[3]);
            int byte = swz(row, k4 * 8);
            *(f16x4*)(Xh + byte) = h;
            *(f16x4*)(Xl + byte) = l;
        }
    }
    __syncthreads();

    const int w  = t >> 6, l = t & 63;
    const int lr = l & 15, lg = l >> 4;
    const int arow = w * 16 + lr;

    f32x4 acc[NCT];
#pragma unroll
    for (int ct = 0; ct < NCT; ++ct) acc[ct] = (f32x4){0.f, 0.f, 0.f, 0.f};

#pragma unroll
    for (int kt = 0; kt < 4; ++kt) {
        const int ka = kt * 64 + 8 * lg;
        f16x4 al0 = *(const f16x4*)(Xh + swz(arow, ka));
        f16x4 al1 = *(const f16x4*)(Xh + swz(arow, ka + 32));
        f16x4 am0 = *(const f16x4*)(Xl + swz(arow, ka));
        f16x4 am1 = *(const f16x4*)(Xl + swz(arow, ka + 32));
        f16x8 a_h = __builtin_shufflevector(al0, al1, 0, 1, 2, 3, 4, 5, 6, 7);
        f16x8 a_l = __builtin_shufflevector(am0, am1, 0, 1, 2, 3, 4, 5, 6, 7);
#pragma unroll
        for (int ct = 0; ct < NCT; ++ct) {
            const int col = ct * 16 + lr;
            f16x4 b0 = *(const f16x4*)(Wh + swz(col, ka));
            f16x4 b1 = *(const f16x4*)(Wh + swz(col, ka + 32));
            f16x4 c0 = *(const f16x4*)(Wl + swz(col, ka));
            f16x4 c1 = *(const f16x4*)(Wl + swz(col, ka + 32));
            f16x8 b_h = __builtin_shufflevector(b0, b1, 0, 1, 2, 3, 4, 5, 6, 7);
            f16x8 b_l = __builtin_shufflevector(c0, c1, 0, 1, 2, 3, 4, 5, 6, 7);
            acc[ct] = __builtin_amdgcn_mfma_f32_16x16x32_f16(a_h, b_h, acc[ct], 0, 0, 0);
            acc[ct] = __builtin_amdgcn_mfma_f32_16x16x32_f16(a_l, b_h, acc[ct], 0, 0, 0);
            acc[ct] = __builtin_amdgcn_mfma_f32_16x16x32_f16(a_h, b_l, acc[ct], 0, 0, 0);
        }
    }

    // feat write (fp16)
#pragma unroll
    for (int ct = 0; ct < NCT; ++ct)
#pragma unroll
        for (int r = 0; r < 4; ++r) {
            int grow = r0 + w * 16 + lg * 4 + r;
            if (grow < n)
                feat[(size_t)grow * NCOL + ct * 16 + lr] = __float2half(acc[ct][r]);
        }

    // fused attention halves: per row, per head: sum_col acc*a  (16-lane reduce)
    float as[NCT], av[NCT];
#pragma unroll
    for (int ct = 0; ct < NCT; ++ct) {
        as[ct] = a_src[ct * 16 + lr];
        av[ct] = a_dst[ct * 16 + lr];
    }
#pragma unroll
    for (int r = 0; r < 4; ++r) {
        int grow = r0 + w * 16 + lg * 4 + r;
#pragma unroll
        for (int h = 0; h < HEADS; ++h) {
            float s = 0.f, d = 0.f;
#pragma unroll
            for (int q = 0; q < CTH; ++q) {
                int ct = h * CTH + q;
                s += acc[ct][r] * as[ct];
                d += acc[ct][r] * av[ct];
            }
#pragma unroll
            for (int o = 1; o < 16; o <<= 1) {
                s += __shfl_xor(s, o);
                d += __shfl_xor(d, o);
            }
            if (lr == 0 && grow < n) {
                alsrc[grow * HEADS + h] = s;
                aldst[grow * HEADS + h] = d;
            }
        }
    }
}

// ==================== fused softmax + aggregation (one wave per dst node)
// Round-6 proven structure: single continuous gather stream, per-lane expf
// (redundant but hidden under memory latency), no LDS. unroll 4 doubles the
// in-flight gather bytes vs round 6 (MLP: 4KB/wave).
template <int OUTC, int HEADS, bool DO_ELU>
__global__ __launch_bounds__(256) void aggregate_kernel(
    const int* __restrict__ csr_off, const int* __restrict__ csr_src,
    const float* __restrict__ alsrc, const float* __restrict__ aldst,
    const __half* __restrict__ feat, const float* __restrict__ bias,
    float* __restrict__ out, int n) {
    constexpr int CPL = 8;            // cols per lane (16B of fp16)
    constexpr int LPE = OUTC / CPL;   // lanes per edge slot: 16 (L1) / 8 (L2)
    constexpr int EPW = 64 / LPE;     // edge slots per wave:  4 / 8
    constexpr int HID = OUTC / HEADS;
    int node = blockIdx.x * 4 + (threadIdx.x >> 6);
    int lane = threadIdx.x & 63;
    if (node >= n) return;
    int off = csr_off[node];
    int deg = csr_off[node + 1] - off;

    const int   sub = lane / LPE;
    const int   l   = lane % LPE;        // cols [CPL*l, CPL*l+CPL)
    const int   h   = (CPL * l) / HID;
    const float ad  = aldst[node * HEADS + h];

    float acc[CPL];
#pragma unroll
    for (int c = 0; c < CPL; ++c) acc[c] = 0.f;
    float sume = 0.f;

#pragma unroll 4
    for (int i = sub; i < deg; i += EPW) {
        int   s = csr_src[off + i];
        float e = alsrc[(size_t)s * HEADS + h] + ad;   // small table, L2-resident
        e = LRELU(e);
        float p = __expf(e);
        sume += p;
        const float4   fv = *(const float4*)(feat + (size_t)s * OUTC + CPL * l);
        const __half2* hp = (const __half2*)&fv;
#pragma unroll
        for (int c2 = 0; c2 < 4; ++c2) {
            float2 f2 = __half22float2(hp[c2]);
            acc[2 * c2 + 0] += p * f2.x;
            acc[2 * c2 + 1] += p * f2.y;
        }
    }
#pragma unroll
    for (int o = LPE; o < 64; o <<= 1) {   // cross-sub butterfly (disjoint edge sets)
#pragma unroll
        for (int c = 0; c < CPL; ++c) acc[c] += __shfl_xor(acc[c], o);
        sume += __shfl_xor(sume, o);
    }
    if (sub == 0) {
        const float inv = 1.f / sume;      // deg >= 1 (self-loop)
        float v[CPL];
#pragma unroll
        for (int c = 0; c < CPL; ++c) {
            v[c] = acc[c] * inv + bias[CPL * l + c];
            if (DO_ELU) v[c] = (v[c] > 0.f) ? v[c] : expm1f(v[c]);
        }
        float* op = out + (size_t)node * OUTC + CPL * l;
        *(float4*)(op + 0) = make_float4(v[0], v[1], v[2], v[3]);
        *(float4*)(op + 4) = make_float4(v[4], v[5], v[6], v[7]);
    }
}

// ----------------------------------------------------------------- launcher
extern "C" void kernel_launch(void* const* d_in, const int* in_sizes, int n_in,
                              void* d_out, int out_size, void* d_ws, size_t ws_size,
                              hipStream_t stream) {
    const float* x   = (const float*)d_in[0];
    const int*   ei  = (const int*)d_in[1];
    const float* W1  = (const float*)d_in[2];
    const float* a1s = (const float*)d_in[3];
    const float* a1d = (const float*)d_in[4];
    const float* b1  = (const float*)d_in[5];
    const float* W2  = (const float*)d_in[6];
    const float* a2s = (const float*)d_in[7];
    const float* a2d = (const float*)d_in[8];
    const float* b2  = (const float*)d_in[9];
    float*       out = (float*)d_out;

    constexpr int IN_C = 128, HEADS = 4, OUTC1 = 128, OUTC2 = 64;
    const int n    = in_sizes[0] / IN_C;
    const int E    = in_sizes[1] / 2;
    const int tot  = E + n;
    const int nbuk = (n + NPB - 1) / NPB;

    char* w = (char*)d_ws;
    auto  alloc = [&](size_t bytes) -> char* {
        char* p = w;
        w += (bytes + 255) & ~(size_t)255;
        return p;
    };
    int*    bcnt    = (int*)alloc((size_t)MAXBUK * 4);
    int*    boff    = (int*)alloc((size_t)(MAXBUK + 1) * 4);
    int*    bcur    = (int*)alloc((size_t)MAXBUK * 4);
    int*    csr_off = (int*)alloc((size_t)(n + 1) * 4);
    int*    csr_src = (int*)alloc((size_t)tot * 4);
    size_t  be_sz   = (size_t)tot * 4 > (size_t)2 * n * 4 ? (size_t)tot * 4
                                                          : (size_t)2 * n * 4;
    unsigned int* be = (unsigned int*)alloc(be_sz);   // packed (src | dlocal<<16)
    size_t  csr_need = (size_t)(w - (char*)d_ws);
    f16*    wh1     = (f16*)alloc(128 * 256);
    f16*    wl1     = (f16*)alloc(128 * 256);
    f16*    wh2     = (f16*)alloc(64 * 256);
    f16*    wl2     = (f16*)alloc(64 * 256);
    float*  alsrc1  = (float*)alloc((size_t)n * HEADS * 4);
    float*  aldst1  = (float*)alloc((size_t)n * HEADS * 4);
    float*  alsrc2  = (float*)alloc((size_t)n * 4);
    float*  aldst2  = (float*)alloc((size_t)n * 4);
    __half* feat_h  = (__half*)alloc((size_t)n * OUTC1 * 2);
    float*  y1      = (float*)alloc((size_t)n * OUTC1 * 4);
    const bool new_csr = (nbuk <= MAXBUK) && (csr_need <= ws_size);

    // ---- W prep (both layers)
    prep_w_kernel<<<(128 * OUTC1 + 255) / 256, 256, 0, stream>>>(W1, wh1, wl1, OUTC1);
    prep_w_kernel<<<(128 * OUTC2 + 255) / 256, 256, 0, stream>>>(W2, wh2, wl2, OUTC2);

    // ---- CSR (shared by both layers)
    if (new_csr) {
        const int g1 = (tot + EPB - 1) / EPB;
        zero_kernel<<<(nbuk + 255) / 256, 256, 0, stream>>>(bcnt, nbuk);
        bucket_hist_kernel<<<g1, 256, 0, stream>>>(ei, bcnt, E, tot, nbuk);
        bucket_scan_kernel<<<1, 512, 0, stream>>>(bcnt, boff, bcur, csr_off, nbuk, n, tot);
        bucket_scatter_kernel<<<g1, 256, 0, stream>>>(ei, bcur, be, E, tot, nbuk);
        csr_build_kernel<<<nbuk, 256, 0, stream>>>(be, boff, csr_off, csr_src, n);
    } else {
        int* counts = (int*)be;
        int* cursor = counts + n;
        zero_kernel<<<(n + 255) / 256, 256, 0, stream>>>(counts, n);
        hist_kernel<<<(tot + 255) / 256, 256, 0, stream>>>(ei, counts, E, tot);
        scan_kernel<<<1, 1024, 0, stream>>>(counts, csr_off, cursor, n);
        scatter_kernel<<<(tot + 255) / 256, 256, 0, stream>>>(ei, cursor, csr_src, E, tot);
    }

    const int gblk = (n + 63) / 64;
    // ---- layer 1: GATConv(128 -> 4 x 32), concat, +b1, ELU
    gemm_mfma_kernel<OUTC1, HEADS><<<gblk, 256, 0, stream>>>(
        x, wh1, wl1, a1s, a1d, feat_h, alsrc1, aldst1, n);
    aggregate_kernel<OUTC1, HEADS, true><<<(n + 3) / 4, 256, 0, stream>>>(
        csr_off, csr_src, alsrc1, aldst1, feat_h, b1, y1, n);

    // ---- layer 2: GATConv(128 -> 1 x 64), +b2
    gemm_mfma_kernel<OUTC2, 1><<<gblk, 256, 0, stream>>>(
        y1, wh2, wl2, a2s, a2d, feat_h, alsrc2, aldst2, n);
    aggregate_kernel<OUTC2, 1, false><<<(n + 3) / 4, 256, 0, stream>>>(
        csr_off, csr_src, alsrc2, aldst2, feat_h, b2, out, n);
}

// Round 9
// 224.626 us; speedup vs baseline: 1.1019x; 1.0420x over previous
//
#include <hip/hip_runtime.h>
#include <hip/hip_fp16.h>

#define LRELU(v) ((v) > 0.f ? (v) : 0.2f * (v))

typedef _Float16 f16;
typedef __attribute__((ext_vector_type(4))) _Float16 f16x4;
typedef __attribute__((ext_vector_type(8))) _Float16 f16x8;
typedef __attribute__((ext_vector_type(4))) float    f32x4;

// swizzled byte offset inside a [rows][128 halves] LDS/global tile (256B rows)
__device__ __forceinline__ int swz(int row, int kbyte) {
    return (row * 256 + kbyte) ^ ((row & 7) << 4);
}

// ================================================================ CSR build
constexpr int NPB    = 128;
constexpr int MAXBUK = 512;    // n <= 65536  (also guarantees src fits 16 bits)
constexpr int EPB    = 8192;   // edges per block in bucket passes
constexpr int CAP    = 12288;

__global__ void zero_kernel(int* __restrict__ p, int n) {
    int i = blockIdx.x * blockDim.x + threadIdx.x;
    if (i < n) p[i] = 0;
}

__global__ __launch_bounds__(256) void bucket_hist_kernel(
    const int* __restrict__ ei, int* __restrict__ bcnt, int E, int tot, int nbuk) {
    __shared__ int lh[MAXBUK];
    for (int i = threadIdx.x; i < nbuk; i += 256) lh[i] = 0;
    __syncthreads();
    int base = blockIdx.x * EPB;
    int lim  = min(base + EPB, tot);
    for (int e = base + threadIdx.x; e < lim; e += 256) {
        int dst = (e < E) ? ei[E + e] : (e - E);
        atomicAdd(&lh[dst >> 7], 1);
    }
    __syncthreads();
    for (int i = threadIdx.x; i < nbuk; i += 256)
        if (lh[i]) atomicAdd(&bcnt[i], lh[i]);
}

__global__ __launch_bounds__(512) void bucket_scan_kernel(
    const int* __restrict__ bcnt, int* __restrict__ boff, int* __restrict__ bcur,
    int* __restrict__ csr_off, int nbuk, int n, int tot) {
    __shared__ int s[512];
    int t = threadIdx.x;
    int v0 = (t < nbuk) ? bcnt[t] : 0;
    s[t] = v0;
    __syncthreads();
    for (int d = 1; d < 512; d <<= 1) {
        int v = (t >= d) ? s[t - d] : 0;
        __syncthreads();
        s[t] += v;
        __syncthreads();
    }
    if (t < nbuk) {
        int off = s[t] - v0;
        boff[t] = off;
        bcur[t] = off;
    }
    if (t == 0) { boff[nbuk] = tot; csr_off[n] = tot; }
}

// packs (src, dst&127) into one uint: src in [15:0], dlocal in [22:16]
__global__ __launch_bounds__(256) void bucket_scatter_kernel(
    const int* __restrict__ ei, int* __restrict__ bcur,
    unsigned int* __restrict__ be, int E, int tot, int nbuk) {
    __shared__ int lh[MAXBUK];
    __shared__ int lb[MAXBUK];
    for (int i = threadIdx.x; i < nbuk; i += 256) lh[i] = 0;
    __syncthreads();
    int base = blockIdx.x * EPB;
    int lim  = min(base + EPB, tot);
    for (int e = base + threadIdx.x; e < lim; e += 256) {
        int dst = (e < E) ? ei[E + e] : (e - E);
        atomicAdd(&lh[dst >> 7], 1);
    }
    __syncthreads();
    for (int i = threadIdx.x; i < nbuk; i += 256)
        lb[i] = lh[i] ? atomicAdd(&bcur[i], lh[i]) : 0;
    __syncthreads();
    for (int i = threadIdx.x; i < nbuk; i += 256) lh[i] = 0;
    __syncthreads();
    for (int e = base + threadIdx.x; e < lim; e += 256) {
        int src, dst;
        if (e < E) { src = ei[e]; dst = ei[E + e]; }
        else       { src = dst = e - E; }
        int b = dst >> 7;
        int p = lb[b] + atomicAdd(&lh[b], 1);
        be[p] = (unsigned)src | ((unsigned)(dst & (NPB - 1)) << 16);
    }
}

__global__ __launch_bounds__(256) void csr_build_kernel(
    const unsigned int* __restrict__ be, const int* __restrict__ boff,
    int* __restrict__ csr_off, int* __restrict__ csr_src, int n) {
    __shared__ int hist[NPB];
    __shared__ int sc[NPB];
    __shared__ int cur[NPB];
    __shared__ int stage[CAP];
    const int b = blockIdx.x, t = threadIdx.x;
    const int start = boff[b], end = boff[b + 1], cnt = end - start;
    if (t < NPB) hist[t] = 0;
    __syncthreads();
    for (int i = t; i < cnt; i += 256)
        atomicAdd(&hist[be[start + i] >> 16], 1);
    __syncthreads();
    if (t < NPB) sc[t] = hist[t];
    __syncthreads();
    for (int d = 1; d < NPB; d <<= 1) {
        int v = (t < NPB && t >= d) ? sc[t - d] : 0;
        __syncthreads();
        if (t < NPB) sc[t] += v;
        __syncthreads();
    }
    if (t < NPB) {
        int excl = sc[t] - hist[t];
        cur[t] = excl;
        int node = b * NPB + t;
        if (node < n) csr_off[node] = start + excl;
    }
    __syncthreads();
    if (cnt <= CAP) {
        for (int i = t; i < cnt; i += 256) {
            unsigned v = be[start + i];
            int p = atomicAdd(&cur[v >> 16], 1);
            stage[p] = (int)(v & 0xFFFFu);
        }
        __syncthreads();
        for (int i = t; i < cnt; i += 256) csr_src[start + i] = stage[i];
    } else {
        for (int i = t; i < cnt; i += 256) {
            unsigned v = be[start + i];
            int p = atomicAdd(&cur[v >> 16], 1);
            csr_src[start + p] = (int)(v & 0xFFFFu);
        }
    }
}

// ---------------- legacy CSR path (fallback, n > 65536 etc.)
__global__ void hist_kernel(const int* __restrict__ ei, int* __restrict__ counts,
                            int E, int tot) {
    int e = blockIdx.x * blockDim.x + threadIdx.x;
    if (e >= tot) return;
    int dst = (e < E) ? ei[E + e] : (e - E);
    atomicAdd(&counts[dst], 1);
}

__global__ __launch_bounds__(1024) void scan_kernel(const int* __restrict__ counts,
                                                    int* __restrict__ csr_off,
                                                    int* __restrict__ cursor, int n) {
    __shared__ int part[1024];
    int t = threadIdx.x;
    int chunk = (n + 1023) >> 10;
    int lo = t * chunk, hi = min(lo + chunk, n);
    int sum = 0;
    for (int i = lo; i < hi; ++i) sum += counts[i];
    part[t] = sum;
    __syncthreads();
    for (int d = 1; d < 1024; d <<= 1) {
        int add = (t >= d) ? part[t - d] : 0;
        __syncthreads();
        part[t] += add;
        __syncthreads();
    }
    int run = part[t] - sum;
    for (int i = lo; i < hi; ++i) {
        csr_off[i] = run;
        cursor[i]  = run;
        run += counts[i];
    }
    if (t == 1023) csr_off[n] = part[1023];
}

__global__ void scatter_kernel(const int* __restrict__ ei, int* __restrict__ cursor,
                               int* __restrict__ csr_src, int E, int tot) {
    int e = blockIdx.x * blockDim.x + threadIdx.x;
    if (e >= tot) return;
    int src, dst;
    if (e < E) { src = ei[e]; dst = ei[E + e]; }
    else       { src = dst = e - E; }
    int pos = atomicAdd(&cursor[dst], 1);
    csr_src[pos] = src;
}

// ============================================ W prep: transpose+split+swizzle
__global__ void prep_w_kernel(const float* __restrict__ W, f16* __restrict__ WhT,
                              f16* __restrict__ WlT, int ncol) {
    int idx = blockIdx.x * 256 + threadIdx.x;
    if (idx >= 128 * ncol) return;
    int k = idx / ncol, c = idx % ncol;
    float v = W[idx];
    f16 h = (f16)v;
    f16 l = (f16)(v - (float)h);
    int byte = swz(c, k * 2);
    *(f16*)((char*)WhT + byte) = h;
    *(f16*)((char*)WlT + byte) = l;
}

// ============================================ split-fp16 MFMA GEMM (round-6 form)
// feat[n,NCOL](f16) = x[n,128](f32) @ W[128,NCOL]  (3-term split fp16 MFMA)
// C/D frag: col = ct*16 + (lane&15), row = (lane>>4)*4 + reg  [m89-verified].
template <int NCOL>
__global__ __launch_bounds__(256) void gemm_mfma_kernel(
    const float* __restrict__ x, const f16* __restrict__ WhT,
    const f16* __restrict__ WlT, __half* __restrict__ feat, int n) {
    constexpr int ROWS = 64;
    constexpr int NCT  = NCOL / 16;
    __shared__ char Xh[ROWS * 256];
    __shared__ char Xl[ROWS * 256];
    __shared__ char Wh[NCOL * 256];
    __shared__ char Wl[NCOL * 256];
    const int t  = threadIdx.x;
    const int r0 = blockIdx.x * ROWS;

    {   // stage W: linear copy (pre-swizzled in global)
        const float4* sh = (const float4*)WhT;
        const float4* sl = (const float4*)WlT;
        float4* dh = (float4*)Wh;
        float4* dl = (float4*)Wl;
        for (int i = t; i < NCOL * 16; i += 256) { dh[i] = sh[i]; dl[i] = sl[i]; }
    }
    {   // stage X: fp32 -> (hi,lo) f16, swizzled
        const float4* X4 = (const float4*)x;
        for (int i = t; i < ROWS * 32; i += 256) {
            int row = i >> 5, k4 = i & 31;
            float4 v = (r0 + row < n) ? X4[(size_t)(r0 + row) * 32 + k4]
                                      : make_float4(0.f, 0.f, 0.f, 0.f);
            f16x4 h, l;
            h[0] = (f16)v.x; l[0] = (f16)(v.x - (float)h[0]);
            h[1] = (f16)v.y; l[1] = (f16)(v.y - (float)h[1]);
            h[2] = (f16)v.z; l[2] = (f16)(v.z - (float)h[2]);
            h[3] = (f16)v.w; l[3] = (f16)(v.w - (float)h[3]);
            int byte = swz(row, k4 * 8);
            *(f16x4*)(Xh + byte) = h;
            *(f16x4*)(Xl + byte) = l;
        }
    }
    __syncthreads();

    const int w  = t >> 6, l = t & 63;
    const int lr = l & 15, lg = l >> 4;
    const int arow = w * 16 + lr;

    f32x4 acc[NCT];
#pragma unroll
    for (int ct = 0; ct < NCT; ++ct) acc[ct] = (f32x4){0.f, 0.f, 0.f, 0.f};

#pragma unroll
    for (int kt = 0; kt < 4; ++kt) {
        const int ka = kt * 64 + 8 * lg;
        f16x4 al0 = *(const f16x4*)(Xh + swz(arow, ka));
        f16x4 al1 = *(const f16x4*)(Xh + swz(arow, ka + 32));
        f16x4 am0 = *(const f16x4*)(Xl + swz(arow, ka));
        f16x4 am1 = *(const f16x4*)(Xl + swz(arow, ka + 32));
        f16x8 a_h = __builtin_shufflevector(al0, al1, 0, 1, 2, 3, 4, 5, 6, 7);
        f16x8 a_l = __builtin_shufflevector(am0, am1, 0, 1, 2, 3, 4, 5, 6, 7);
#pragma unroll
        for (int ct = 0; ct < NCT; ++ct) {
            const int col = ct * 16 + lr;
            f16x4 b0 = *(const f16x4*)(Wh + swz(col, ka));
            f16x4 b1 = *(const f16x4*)(Wh + swz(col, ka + 32));
            f16x4 c0 = *(const f16x4*)(Wl + swz(col, ka));
            f16x4 c1 = *(const f16x4*)(Wl + swz(col, ka + 32));
            f16x8 b_h = __builtin_shufflevector(b0, b1, 0, 1, 2, 3, 4, 5, 6, 7);
            f16x8 b_l = __builtin_shufflevector(c0, c1, 0, 1, 2, 3, 4, 5, 6, 7);
            acc[ct] = __builtin_amdgcn_mfma_f32_16x16x32_f16(a_h, b_h, acc[ct], 0, 0, 0);
            acc[ct] = __builtin_amdgcn_mfma_f32_16x16x32_f16(a_l, b_h, acc[ct], 0, 0, 0);
            acc[ct] = __builtin_amdgcn_mfma_f32_16x16x32_f16(a_h, b_l, acc[ct], 0, 0, 0);
        }
    }

#pragma unroll
    for (int ct = 0; ct < NCT; ++ct)
#pragma unroll
        for (int r = 0; r < 4; ++r) {
            int grow = r0 + w * 16 + lg * 4 + r;
            if (grow < n)
                feat[(size_t)grow * NCOL + ct * 16 + lr] = __float2half(acc[ct][r]);
        }
}

// ============================================ attention halves from feat_h
template <int OUTC, int HEADS>
__global__ __launch_bounds__(256) void al_kernel(
    const __half* __restrict__ feat, const float* __restrict__ a_src,
    const float* __restrict__ a_dst, float* __restrict__ alsrc,
    float* __restrict__ aldst, int n) {
    constexpr int CP  = OUTC / 64;     // halves per lane: 2 (L1) / 1 (L2)
    constexpr int HID = OUTC / HEADS;
    constexpr int G   = HID / CP;      // lanes per head group: 16 / 64
    int node = blockIdx.x * 4 + (threadIdx.x >> 6);
    int lane = threadIdx.x & 63;
    if (node >= n) return;
    float s, d;
    if constexpr (CP == 2) {
        __half2 hv = *(const __half2*)(feat + (size_t)node * OUTC + lane * 2);
        float2  f  = __half22float2(hv);
        s = f.x * a_src[lane * 2] + f.y * a_src[lane * 2 + 1];
        d = f.x * a_dst[lane * 2] + f.y * a_dst[lane * 2 + 1];
    } else {
        float f = __half2float(feat[(size_t)node * OUTC + lane]);
        s = f * a_src[lane];
        d = f * a_dst[lane];
    }
#pragma unroll
    for (int o = G / 2; o > 0; o >>= 1) {
        s += __shfl_xor(s, o);
        d += __shfl_xor(d, o);
    }
    if ((lane & (G - 1)) == 0) {
        int h = lane / G;
        alsrc[node * HEADS + h] = s;
        aldst[node * HEADS + h] = d;
    }
}

// ==================== fused softmax + aggregation (one wave per dst node)
// Single continuous gather stream (round-6 structure). Inner product written
// as scalar (float)f16 * f32 + f32 so the backend emits v_fma_mix_f32
// (cvt folded into the FMA) instead of 8x v_cvt + 8x v_fmac.
template <int OUTC, int HEADS, bool DO_ELU>
__global__ __launch_bounds__(256) void aggregate_kernel(
    const int* __restrict__ csr_off, const int* __restrict__ csr_src,
    const float* __restrict__ alsrc, const float* __restrict__ aldst,
    const __half* __restrict__ feat, const float* __restrict__ bias,
    float* __restrict__ out, int n) {
    constexpr int CPL = 8;            // cols per lane (16B of fp16)
    constexpr int LPE = OUTC / CPL;   // lanes per edge slot: 16 (L1) / 8 (L2)
    constexpr int EPW = 64 / LPE;     // edge slots per wave:  4 / 8
    constexpr int HID = OUTC / HEADS;
    int node = blockIdx.x * 4 + (threadIdx.x >> 6);
    int lane = threadIdx.x & 63;
    if (node >= n) return;
    int off = csr_off[node];
    int deg = csr_off[node + 1] - off;

    const int   sub = lane / LPE;
    const int   l   = lane % LPE;        // cols [CPL*l, CPL*l+CPL)
    const int   h   = (CPL * l) / HID;
    const float ad  = aldst[node * HEADS + h];

    float acc[CPL];
#pragma unroll
    for (int c = 0; c < CPL; ++c) acc[c] = 0.f;
    float sume = 0.f;

#pragma unroll 4
    for (int i = sub; i < deg; i += EPW) {
        int   s = csr_src[off + i];
        float e = alsrc[(size_t)s * HEADS + h] + ad;   // small table, L2-resident
        e = LRELU(e);
        float p = __expf(e);
        sume += p;
        f16x8 fv = *(const f16x8*)(feat + (size_t)s * OUTC + CPL * l);
#pragma unroll
        for (int c = 0; c < CPL; ++c) acc[c] += p * (float)fv[c];   // v_fma_mix
    }
#pragma unroll
    for (int o = LPE; o < 64; o <<= 1) {   // cross-sub butterfly (disjoint edge sets)
#pragma unroll
        for (int c = 0; c < CPL; ++c) acc[c] += __shfl_xor(acc[c], o);
        sume += __shfl_xor(sume, o);
    }
    if (sub == 0) {
        const float inv = 1.f / sume;      // deg >= 1 (self-loop)
        float v[CPL];
#pragma unroll
        for (int c = 0; c < CPL; ++c) {
            v[c] = acc[c] * inv + bias[CPL * l + c];
            if (DO_ELU) v[c] = (v[c] > 0.f) ? v[c] : expm1f(v[c]);
        }
        float* op = out + (size_t)node * OUTC + CPL * l;
        *(float4*)(op + 0) = make_float4(v[0], v[1], v[2], v[3]);
        *(float4*)(op + 4) = make_float4(v[4], v[5], v[6], v[7]);
    }
}

// ----------------------------------------------------------------- launcher
extern "C" void kernel_launch(void* const* d_in, const int* in_sizes, int n_in,
                              void* d_out, int out_size, void* d_ws, size_t ws_size,
                              hipStream_t stream) {
    const float* x   = (const float*)d_in[0];
    const int*   ei  = (const int*)d_in[1];
    const float* W1  = (const float*)d_in[2];
    const float* a1s = (const float*)d_in[3];
    const float* a1d = (const float*)d_in[4];
    const float* b1  = (const float*)d_in[5];
    const float* W2  = (const float*)d_in[6];
    const float* a2s = (const float*)d_in[7];
    const float* a2d = (const float*)d_in[8];
    const float* b2  = (const float*)d_in[9];
    float*       out = (float*)d_out;

    constexpr int IN_C = 128, HEADS = 4, OUTC1 = 128, OUTC2 = 64;
    const int n    = in_sizes[0] / IN_C;
    const int E    = in_sizes[1] / 2;
    const int tot  = E + n;
    const int nbuk = (n + NPB - 1) / NPB;

    char* w = (char*)d_ws;
    auto  alloc = [&](size_t bytes) -> char* {
        char* p = w;
        w += (bytes + 255) & ~(size_t)255;
        return p;
    };
    int*    bcnt    = (int*)alloc((size_t)MAXBUK * 4);
    int*    boff    = (int*)alloc((size_t)(MAXBUK + 1) * 4);
    int*    bcur    = (int*)alloc((size_t)MAXBUK * 4);
    int*    csr_off = (int*)alloc((size_t)(n + 1) * 4);
    int*    csr_src = (int*)alloc((size_t)tot * 4);
    size_t  be_sz   = (size_t)tot * 4 > (size_t)2 * n * 4 ? (size_t)tot * 4
                                                          : (size_t)2 * n * 4;
    unsigned int* be = (unsigned int*)alloc(be_sz);   // packed (src | dlocal<<16)
    size_t  csr_need = (size_t)(w - (char*)d_ws);
    f16*    wh1     = (f16*)alloc(128 * 256);
    f16*    wl1     = (f16*)alloc(128 * 256);
    f16*    wh2     = (f16*)alloc(64 * 256);
    f16*    wl2     = (f16*)alloc(64 * 256);
    float*  alsrc1  = (float*)alloc((size_t)n * HEADS * 4);
    float*  aldst1  = (float*)alloc((size_t)n * HEADS * 4);
    float*  alsrc2  = (float*)alloc((size_t)n * 4);
    float*  aldst2  = (float*)alloc((size_t)n * 4);
    __half* feat_h  = (__half*)alloc((size_t)n * OUTC1 * 2);
    float*  y1      = (float*)alloc((size_t)n * OUTC1 * 4);
    const bool new_csr = (nbuk <= MAXBUK) && (csr_need <= ws_size);

    // ---- W prep (both layers)
    prep_w_kernel<<<(128 * OUTC1 + 255) / 256, 256, 0, stream>>>(W1, wh1, wl1, OUTC1);
    prep_w_kernel<<<(128 * OUTC2 + 255) / 256, 256, 0, stream>>>(W2, wh2, wl2, OUTC2);

    // ---- CSR (shared by both layers)
    if (new_csr) {
        const int g1 = (tot + EPB - 1) / EPB;
        zero_kernel<<<(nbuk + 255) / 256, 256, 0, stream>>>(bcnt, nbuk);
        bucket_hist_kernel<<<g1, 256, 0, stream>>>(ei, bcnt, E, tot, nbuk);
        bucket_scan_kernel<<<1, 512, 0, stream>>>(bcnt, boff, bcur, csr_off, nbuk, n, tot);
        bucket_scatter_kernel<<<g1, 256, 0, stream>>>(ei, bcur, be, E, tot, nbuk);
        csr_build_kernel<<<nbuk, 256, 0, stream>>>(be, boff, csr_off, csr_src, n);
    } else {
        int* counts = (int*)be;
        int* cursor = counts + n;
        zero_kernel<<<(n + 255) / 256, 256, 0, stream>>>(counts, n);
        hist_kernel<<<(tot + 255) / 256, 256, 0, stream>>>(ei, counts, E, tot);
        scan_kernel<<<1, 1024, 0, stream>>>(counts, csr_off, cursor, n);
        scatter_kernel<<<(tot + 255) / 256, 256, 0, stream>>>(ei, cursor, csr_src, E, tot);
    }

    const int gblk = (n + 63) / 64;
    // ---- layer 1: GATConv(128 -> 4 x 32), concat, +b1, ELU
    gemm_mfma_kernel<OUTC1><<<gblk, 256, 0, stream>>>(x, wh1, wl1, feat_h, n);
    al_kernel<OUTC1, HEADS><<<(n + 3) / 4, 256, 0, stream>>>(
        feat_h, a1s, a1d, alsrc1, aldst1, n);
    aggregate_kernel<OUTC1, HEADS, true><<<(n + 3) / 4, 256, 0, stream>>>(
        csr_off, csr_src, alsrc1, aldst1, feat_h, b1, y1, n);

    // ---- layer 2: GATConv(128 -> 1 x 64), +b2
    gemm_mfma_kernel<OUTC2><<<gblk, 256, 0, stream>>>(y1, wh2, wl2, feat_h, n);
    al_kernel<OUTC2, 1><<<(n + 3) / 4, 256, 0, stream>>>(
        feat_h, a2s, a2d, alsrc2, aldst2, n);
    aggregate_kernel<OUTC2, 1, false><<<(n + 3) / 4, 256, 0, stream>>>(
        csr_off, csr_src, alsrc2, aldst2, feat_h, b2, out, n);
}